// Round 1
// baseline (115624.878 us; speedup 1.0000x reference)
//
#include <hip/hip_runtime.h>

#define BB 128
#define TT 1000
#define HH 512
#define G4 2048
#define NGRP 8
#define SLOTS 64
#define SEQ_PER_G 16
#define HC_PER_SLOT 8

__device__ __forceinline__ float sigm(float v) { return 1.0f / (1.0f + __expf(-v)); }

// 512 WGs x 256 thr. group = bid&7 (batch slice of 16 seqs), slot = bid>>3
// (8 h-columns -> 32 gate columns). W_hh slice persistent in LDS (64 KB).
// h exchanged via double-buffered global buffer + group barrier each step.
__global__ __launch_bounds__(256, 2)
void lstm_persist(const float* __restrict__ x,     // [B][T][2]
                  const float* __restrict__ wih,   // [2][4H]
                  const float* __restrict__ whh,   // [H][4H]
                  const float* __restrict__ bias,  // [4H]
                  float* __restrict__ out,         // h [B][T][H], then c [B][T][H]
                  float* ws)
{
    __shared__ float wl[32 * 512];   // [cslot=c*4+q][k], XOR-swizzled in k

    const int bid  = blockIdx.x;
    const int g    = bid & 7;
    const int slot = bid >> 3;
    const int tid  = threadIdx.x;
    const int seq  = tid >> 4;          // 0..15
    const int col  = (tid & 15) >> 1;   // 0..7
    const int half = tid & 1;           // 0: gates f,i   1: gates o,g
    const int b    = g * SEQ_PER_G + seq;
    const int hc   = slot * HC_PER_SLOT + col;

    float* hbuf   = ws;                               // [2][BB][HH]
    unsigned* bar = (unsigned*)(ws + 2 * BB * HH);    // [NGRP][64] (256B spacing)

    // ---- one-time: stage W_hh slice into LDS (coalesced-ish 32B chunks) ----
    for (int e = tid; e < 32 * 512; e += 256) {
        int c  = e & 7;
        int q  = (e >> 3) & 3;
        int k  = e >> 5;
        int cs = c * 4 + q;
        wl[cs * 512 + (k ^ ((cs & 7) << 2))] =
            whh[(size_t)k * G4 + q * 512 + slot * HC_PER_SLOT + c];
    }

    // per-thread input weights + bias for its 2 gate columns
    const int q0  = half * 2;
    const int gc0 = q0 * 512 + hc;
    const int gc1 = (q0 + 1) * 512 + hc;
    const float wa0 = wih[gc0], wb0 = wih[G4 + gc0], bs0 = bias[gc0];
    const float wa1 = wih[gc1], wb1 = wih[G4 + gc1], bs1 = bias[gc1];

    const int cs0 = col * 4 + q0;
    const int cs1 = cs0 + 1;
    const int sw0 = (cs0 & 7) << 2;
    const int sw1 = (cs1 & 7) << 2;
    const float* wp0 = wl + cs0 * 512;
    const float* wp1 = wl + cs1 * 512;

    __syncthreads();

    float cst = 0.0f;
    const float* xrow = x + (size_t)b * (TT * 2);
    float* outh = out;
    float* outc = out + (size_t)BB * TT * HH;
    unsigned* mybar = &bar[g * 64];

    for (int t = 0; t < TT; ++t) {
        const float* hrow = hbuf + (size_t)(t & 1) * (BB * HH) + (size_t)b * HH;

        float4 a0 = {0.f, 0.f, 0.f, 0.f};
        float4 a1 = {0.f, 0.f, 0.f, 0.f};
        #pragma unroll 4
        for (int k = 0; k < HH; k += 4) {
            float4 hv = *(const float4*)(hrow + k);
            float4 w0 = *(const float4*)(wp0 + (k ^ sw0));
            float4 w1 = *(const float4*)(wp1 + (k ^ sw1));
            a0.x += hv.x * w0.x; a0.y += hv.y * w0.y;
            a0.z += hv.z * w0.z; a0.w += hv.w * w0.w;
            a1.x += hv.x * w1.x; a1.y += hv.y * w1.y;
            a1.z += hv.z * w1.z; a1.w += hv.w * w1.w;
        }
        float x0 = xrow[2 * t], x1 = xrow[2 * t + 1];
        float d0 = (a0.x + a0.y) + (a0.z + a0.w) + x0 * wa0 + x1 * wb0 + bs0;
        float d1 = (a1.x + a1.y) + (a1.z + a1.w) + x0 * wa1 + x1 * wb1 + bs1;

        // pair exchange: half0 holds (f,i), half1 holds (o,g)
        float o0 = __shfl_xor(d0, 1);
        float o1 = __shfl_xor(d1, 1);
        float gf = (half == 0) ? d0 : o0;
        float gi = (half == 0) ? d1 : o1;
        float go = (half == 0) ? o0 : d0;
        float gg = (half == 0) ? o1 : d1;

        float c1 = sigm(gf) * cst + sigm(gi) * tanhf(gg);
        float h1 = sigm(go) * tanhf(c1);
        cst = c1;

        if (half == 0) {
            hbuf[(size_t)((t + 1) & 1) * (BB * HH) + (size_t)b * HH + hc] = h1;
            size_t oidx = (size_t)b * (TT * HH) + (size_t)t * HH + hc;
            outh[oidx] = h1;
            outc[oidx] = c1;
        }

        // ---- group barrier (release h writes, acquire others') ----
        __syncthreads();
        __threadfence();
        if (tid == 0) {
            __hip_atomic_fetch_add(mybar, 1u, __ATOMIC_ACQ_REL, __HIP_MEMORY_SCOPE_AGENT);
            unsigned tgt = (unsigned)(t + 1) * SLOTS;
            long guard = 0;
            while (__hip_atomic_load(mybar, __ATOMIC_ACQUIRE, __HIP_MEMORY_SCOPE_AGENT) < tgt) {
                __builtin_amdgcn_s_sleep(1);
                if (++guard > 200000000L) break;   // anti-hang escape
            }
        }
        __syncthreads();
        __threadfence();
    }
}

extern "C" void kernel_launch(void* const* d_in, const int* in_sizes, int n_in,
                              void* d_out, int out_size, void* d_ws, size_t ws_size,
                              hipStream_t stream) {
    const float* x    = (const float*)d_in[0];
    const float* wih  = (const float*)d_in[1];
    const float* whh  = (const float*)d_in[2];
    const float* bias = (const float*)d_in[3];
    float* out = (float*)d_out;
    float* ws  = (float*)d_ws;

    // zero h double-buffer + barrier counters (re-zeroed on every replay)
    size_t zero_bytes = (size_t)(2 * BB * HH) * sizeof(float) + NGRP * 64 * sizeof(unsigned);
    hipMemsetAsync(d_ws, 0, zero_bytes, stream);

    dim3 grid(NGRP * SLOTS), block(256);
    hipLaunchKernelGGL(lstm_persist, grid, block, 0, stream, x, wih, whh, bias, out, ws);
}

// Round 2
// 8322.261 us; speedup vs baseline: 13.8934x; 13.8934x over previous
//
#include <hip/hip_runtime.h>

#define TT 1000
#define HH 512
#define G4 2048
#define NGRP 4
#define SPG 32        // seqs per group
#define SLOTS 64      // blocks per group
#define GCB 32        // gate-cols per block
#define HCB 8         // h-cols per block

typedef __attribute__((ext_vector_type(8))) short bf16x8;
typedef __attribute__((ext_vector_type(4))) float f32x4;

__device__ __forceinline__ float sigm(float v) { return 1.0f / (1.0f + __expf(-v)); }

__device__ __forceinline__ unsigned short bf16rne(float f) {
    unsigned u = __float_as_uint(f);
    return (unsigned short)((u + 0x7fffu + ((u >> 16) & 1u)) >> 16);
}

// 256 blocks x 256 thr (1/CU). group g = bid&3 owns seqs [g*32, g*32+32);
// slot = bid>>2 owns h-cols [slot*8, slot*8+8) -> 32 gate-cols.
// W_hh slice bf16 in LDS (swizzled), h staged bf16 in LDS (swizzled).
// h exchanged via RELAXED agent-scope atomics only (no fences, no L2 flush).
__global__ __launch_bounds__(256, 1)
void lstm_mfma(const float* __restrict__ x,     // [B][T][2]
               const float* __restrict__ wih,   // [2][4H]
               const float* __restrict__ whh,   // [H][4H]
               const float* __restrict__ bias,  // [4H]
               float* __restrict__ out,         // h [B][T][H] then c [B][T][H]
               float* ws)
{
    __shared__ short wsh[GCB * 512];   // [gcl][k^swz] bf16  (32 KB)
    __shared__ short hsh[SPG * 512];   // [seq][k^swz] bf16  (32 KB)

    const int bid  = blockIdx.x;
    const int g    = bid & (NGRP - 1);
    const int slot = bid >> 2;
    const int tid  = threadIdx.x;
    const int wv   = tid >> 6;
    const int lane = tid & 63;
    const int sh   = wv >> 1;          // seq half (16 rows)
    const int ch   = wv & 1;           // col half (16 gate-cols)
    const int col  = lane & 15;
    const int kb   = lane >> 4;        // 0..3
    const int g0   = col & 3;          // gate id (0=f,1=i,2=o,3=g)
    const int hlw  = col >> 2;         // 0..3 local h-col within wave
    const int ghcol = slot * HCB + ch * 4 + hlw;
    const int gc_glob = g0 * 512 + ghcol;

    unsigned short* hbuf = (unsigned short*)ws;                 // bf16 [2][128][512]
    unsigned* bar = (unsigned*)((char*)ws + 256 * 1024);        // [NGRP][64]

    // zero h LDS (t=0 state)
    for (int i = tid; i < SPG * 512 / 2; i += 256)
        ((unsigned*)hsh)[i] = 0u;

    // stage W_hh slice as bf16, XOR-swizzled in k
    for (int e = tid; e < GCB * 512; e += 256) {
        int gcl = e & 31, k = e >> 5;
        int gate = gcl & 3, hl = gcl >> 2;
        float w = whh[(size_t)k * G4 + gate * 512 + slot * HCB + hl];
        wsh[gcl * 512 + (k ^ ((gcl & 7) << 3))] = (short)bf16rne(w);
    }

    const float wA = wih[gc_glob];
    const float wB = wih[G4 + gc_glob];
    const float bs = bias[gc_glob];

    const int seq0 = sh * 16 + kb * 4;         // first of this lane's 4 C rows
    const int b0   = g * SPG + seq0;           // global batch index base

    const int aRow = sh * 16 + (lane & 15);
    const int aSw  = (aRow & 7) << 3;
    const int gclB = ch * 16 + (lane & 15);
    const int bSw  = (gclB & 7) << 3;
    const short* aBase = hsh + aRow * 512;
    const short* bBase = wsh + gclB * 512;
    const int kOff = kb * 8;

    __syncthreads();

    float cst[4] = {0.f, 0.f, 0.f, 0.f};
    unsigned* mybar = &bar[g * 64];
    const size_t OSZ = (size_t)128 * TT * HH;

    #pragma unroll 1
    for (int t = 0; t < TT; ++t) {
        // x inputs for this lane's 4 rows (plain cached loads)
        float x0[4], x1[4];
        #pragma unroll
        for (int r = 0; r < 4; ++r) {
            const float2 xv = *(const float2*)(x + ((size_t)(b0 + r) * TT + t) * 2);
            x0[r] = xv.x; x1[r] = xv.y;
        }

        // gates = h @ W_hh  (MFMA, K=512)
        f32x4 acc = {0.f, 0.f, 0.f, 0.f};
        #pragma unroll
        for (int kt = 0; kt < 16; ++kt) {
            int kbase = kt * 32 + kOff;
            bf16x8 af = *(const bf16x8*)(aBase + (kbase ^ aSw));
            bf16x8 bfr = *(const bf16x8*)(bBase + (kbase ^ bSw));
            acc = __builtin_amdgcn_mfma_f32_16x16x32_bf16(af, bfr, acc, 0, 0, 0);
        }

        // + x @ W_ih + bias
        float v[4];
        #pragma unroll
        for (int r = 0; r < 4; ++r)
            v[r] = acc[r] + x0[r] * wA + x1[r] * wB + bs;

        // butterfly across the 4-gate quad (lanes differing in bits 0-1)
        float hv4[4], cv4[4];
        #pragma unroll
        for (int r = 0; r < 4; ++r) {
            float p1 = __shfl_xor(v[r], 1);
            float p2 = __shfl_xor(v[r], 2);
            float p3 = __shfl_xor(p1, 2);
            // value of gate q is at XOR-distance d=q^g0: [v,p1,p2,p3][d]
            int df = g0, di = g0 ^ 1, dov = g0 ^ 2, dg = g0 ^ 3;
            float fv = (df & 2) ? ((df & 1) ? p3 : p2) : ((df & 1) ? p1 : v[r]);
            float iv = (di & 2) ? ((di & 1) ? p3 : p2) : ((di & 1) ? p1 : v[r]);
            float ov = (dov & 2) ? ((dov & 1) ? p3 : p2) : ((dov & 1) ? p1 : v[r]);
            float gv = (dg & 2) ? ((dg & 1) ? p3 : p2) : ((dg & 1) ? p1 : v[r]);
            float c1 = sigm(fv) * cst[r] + sigm(iv) * tanhf(gv);
            float h1 = sigm(ov) * tanhf(c1);
            cst[r] = c1;
            hv4[r] = h1; cv4[r] = c1;
        }

        // each quad-lane writes row r = g0 (unique (b, ghcol) per lane)
        float hsel = (g0 & 2) ? ((g0 & 1) ? hv4[3] : hv4[2]) : ((g0 & 1) ? hv4[1] : hv4[0]);
        float csel = (g0 & 2) ? ((g0 & 1) ? cv4[3] : cv4[2]) : ((g0 & 1) ? cv4[1] : cv4[0]);
        const int bsel = b0 + g0;
        size_t oidx = ((size_t)bsel * TT + t) * HH + ghcol;
        out[oidx] = hsel;
        out[OSZ + oidx] = csel;

        if (t + 1 < TT) {
            // gather 4 h-cols into hlw==0 lanes, pack 4xbf16, one u64 atomic store
            float q1 = __shfl_xor(hsel, 4);
            float q2 = __shfl_xor(hsel, 8);
            float q3 = __shfl_xor(q1, 8);
            if (hlw == 0) {
                unsigned long long pk =
                      (unsigned long long)bf16rne(hsel)
                    | ((unsigned long long)bf16rne(q1) << 16)
                    | ((unsigned long long)bf16rne(q2) << 32)
                    | ((unsigned long long)bf16rne(q3) << 48);
                size_t hidx = ((size_t)((t + 1) & 1) * 128 + bsel) * 512 + slot * HCB + ch * 4;
                __hip_atomic_store((unsigned long long*)(hbuf + hidx), pk,
                                   __ATOMIC_RELAXED, __HIP_MEMORY_SCOPE_AGENT);
            }
            asm volatile("s_waitcnt vmcnt(0)" ::: "memory");
            __syncthreads();

            // group barrier: relaxed add + relaxed spin (no cache maintenance)
            if (tid == 0) {
                __hip_atomic_fetch_add(mybar, 1u, __ATOMIC_RELAXED, __HIP_MEMORY_SCOPE_AGENT);
                const unsigned tgt = (unsigned)(t + 1) * SLOTS;
                long gd = 0;
                while (__hip_atomic_load(mybar, __ATOMIC_RELAXED, __HIP_MEMORY_SCOPE_AGENT) < tgt) {
                    __builtin_amdgcn_s_sleep(1);
                    if (++gd > 100000000L) break;   // anti-hang escape
                }
            }
            __syncthreads();

            // refill hsh with the group's full h(t+1): 4096 u64 atomic loads/block
            const unsigned long long* src = (const unsigned long long*)
                (hbuf + ((size_t)((t + 1) & 1) * 128 + g * SPG) * 512);
            #pragma unroll
            for (int i = 0; i < 16; ++i) {
                int idx = i * 256 + tid;           // u64 index, 0..4095
                unsigned long long d = __hip_atomic_load(src + idx,
                        __ATOMIC_RELAXED, __HIP_MEMORY_SCOPE_AGENT);
                int seql = idx >> 7;               // 128 u64 per 512-bf16 row
                int k0   = (idx & 127) << 2;
                ((unsigned long long*)hsh)[(seql * 512 + (k0 ^ ((seql & 7) << 3))) >> 2] = d;
            }
            __syncthreads();
        }
    }
}

extern "C" void kernel_launch(void* const* d_in, const int* in_sizes, int n_in,
                              void* d_out, int out_size, void* d_ws, size_t ws_size,
                              hipStream_t stream) {
    const float* x    = (const float*)d_in[0];
    const float* wih  = (const float*)d_in[1];
    const float* whh  = (const float*)d_in[2];
    const float* bias = (const float*)d_in[3];
    float* out = (float*)d_out;
    float* ws  = (float*)d_ws;

    // zero the barrier counters every launch (graph replay safe)
    hipMemsetAsync((char*)d_ws + 256 * 1024, 0, NGRP * 64 * sizeof(unsigned), stream);

    dim3 grid(NGRP * SLOTS), block(256);
    hipLaunchKernelGGL(lstm_mfma, grid, block, 0, stream, x, wih, whh, bias, out, ws);
}

// Round 4
// 4157.562 us; speedup vs baseline: 27.8107x; 2.0017x over previous
//
#include <hip/hip_runtime.h>

#define TT 1000
#define HH 512
#define G4 2048
#define NGRP 8
#define SPG 16        // seqs per group
#define SLOTS 32      // blocks per group
#define HCB 16        // h-cols per block (64 gate cols)

typedef __attribute__((ext_vector_type(8))) short bf16x8;
typedef __attribute__((ext_vector_type(4))) float f32x4;

__device__ __forceinline__ float sigm(float v) { return 1.0f / (1.0f + __expf(-v)); }
__device__ __forceinline__ float tanh_fast(float v) { return 2.0f / (1.0f + __expf(-2.0f * v)) - 1.0f; }

__device__ __forceinline__ unsigned short bf16rne(float f) {
    unsigned u = __float_as_uint(f);
    return (unsigned short)((u + 0x7fffu + ((u >> 16) & 1u)) >> 16);
}

// 256 blocks x 256 thr (1/CU). group g = bid&7 owns seqs [g*16, g*16+16);
// slot = bid>>3 owns h-cols [slot*16, slot*16+16) -> 64 gate cols.
// W_hh fragments live in VGPRs (loaded once). h staged bf16 in LDS (swizzled).
// Barrier: per-block flag lines (no RMW contention) + one-wave ballot poll.
__global__ __launch_bounds__(256, 1)
void lstm_mfma4(const float* __restrict__ x,     // [B][T][2]
                const float* __restrict__ wih,   // [2][4H]
                const float* __restrict__ whh,   // [H][4H]
                const float* __restrict__ bias,  // [4H]
                float* __restrict__ out,         // h [B][T][H] then c [B][T][H]
                float* ws)
{
    __shared__ short hsh[16 * 512];    // h(t) bf16, swizzled (16 KB)
    __shared__ float hnew[16][16];     // this block's h(t+1) piece
    __shared__ float cnew[16][16];

    const int bid  = blockIdx.x;
    const int g    = bid & (NGRP - 1);
    const int slot = bid >> 3;
    const int tid  = threadIdx.x;
    const int wv   = tid >> 6;
    const int lane = tid & 63;
    const int col  = lane & 15;
    const int kb   = lane >> 4;            // k-subchunk / row-group
    const int q    = col & 3;              // gate id 0=f,1=i,2=o,3=g
    const int q1   = q & 1, q2 = q >> 1;
    const int hl   = wv * 4 + (col >> 2);  // block h-col 0..15
    const int gc   = q * 512 + slot * HCB + hl;   // global gate col
    const int rowSel = kb * 4 + q;         // this lane's owned seq row
    const int bSel   = g * SPG + rowSel;   // global batch index

    unsigned short* hbuf = (unsigned short*)ws;              // bf16 [2][128][512]
    unsigned* flags = (unsigned*)((char*)ws + 256 * 1024);   // [8][32] spaced 64B

    // zero hsh (t=0 state)
    for (int i = tid; i < 4096; i += 256) ((unsigned*)hsh)[i] = 0u;

    // ---- one-time: W_hh fragments straight into registers (64 VGPR) ----
    bf16x8 breg[16];
    #pragma unroll
    for (int kt = 0; kt < 16; ++kt) {
        bf16x8 f;
        #pragma unroll
        for (int j = 0; j < 8; ++j) {
            int k = kt * 32 + kb * 8 + j;
            f[j] = (short)bf16rne(whh[(size_t)k * G4 + gc]);
        }
        breg[kt] = f;
    }

    // per-lane gate constants (all 4 gates at this lane's h-col)
    float wA[4], wB[4], bb[4];
    #pragma unroll
    for (int j = 0; j < 4; ++j) {
        int gcj = j * 512 + slot * HCB + hl;
        wA[j] = wih[gcj]; wB[j] = wih[G4 + gcj]; bb[j] = bias[gcj];
    }

    const int arow = col;
    const int asw  = (arow & 7) << 3;
    const short* aBase = hsh + arow * 512;

    __syncthreads();

    float cst = 0.0f;
    const size_t OSZ = (size_t)128 * TT * HH;
    const float* xp = x + (size_t)bSel * TT * 2;

    for (int t = 0; t < TT; ++t) {
        // ---- gates = h @ W_hh (K=512, MFMA, 2 acc chains) ----
        f32x4 acc0 = {0.f, 0.f, 0.f, 0.f};
        f32x4 acc1 = {0.f, 0.f, 0.f, 0.f};
        #pragma unroll
        for (int kt = 0; kt < 16; kt += 2) {
            int ka = (kt * 32 + kb * 8);
            bf16x8 a0 = *(const bf16x8*)(aBase + (ka ^ asw));
            acc0 = __builtin_amdgcn_mfma_f32_16x16x32_bf16(a0, breg[kt], acc0, 0, 0, 0);
            int kc = ((kt + 1) * 32 + kb * 8);
            bf16x8 a1 = *(const bf16x8*)(aBase + (kc ^ asw));
            acc1 = __builtin_amdgcn_mfma_f32_16x16x32_bf16(a1, breg[kt + 1], acc1, 0, 0, 0);
        }
        float v0 = acc0[0] + acc1[0], v1 = acc0[1] + acc1[1];
        float v2 = acc0[2] + acc1[2], v3 = acc0[3] + acc1[3];

        // ---- quad butterfly: lane ends with all 4 gates of row rowSel ----
        float vq = q2 ? (q1 ? v3 : v2) : (q1 ? v1 : v0);   // v[q]
        float s1 = q2 ? (q1 ? v2 : v3) : (q1 ? v0 : v1);   // v[q^1]
        float s2 = q2 ? (q1 ? v1 : v0) : (q1 ? v3 : v2);   // v[q^2]
        float s3 = q2 ? (q1 ? v0 : v1) : (q1 ? v2 : v3);   // v[q^3]
        float g1 = __shfl_xor(s1, 1);   // gate q^1 at row rowSel
        float g2 = __shfl_xor(s2, 2);   // gate q^2
        float g3 = __shfl_xor(s3, 3);   // gate q^3

        float fv = q2 ? (q1 ? g3 : g2) : (q1 ? g1 : vq);
        float iv = q2 ? (q1 ? g2 : g3) : (q1 ? vq : g1);
        float ov = q2 ? (q1 ? g1 : vq) : (q1 ? g3 : g2);
        float gv = q2 ? (q1 ? vq : g1) : (q1 ? g2 : g3);

        const float2 xv = *(const float2*)(xp + 2 * t);
        fv += xv.x * wA[0] + xv.y * wB[0] + bb[0];
        iv += xv.x * wA[1] + xv.y * wB[1] + bb[1];
        ov += xv.x * wA[2] + xv.y * wB[2] + bb[2];
        gv += xv.x * wA[3] + xv.y * wB[3] + bb[3];

        float c1 = sigm(fv) * cst + sigm(iv) * tanh_fast(gv);
        float h1 = sigm(ov) * tanh_fast(c1);
        cst = c1;
        hnew[rowSel][hl] = h1;
        cnew[rowSel][hl] = c1;

        __syncthreads();

        // ---- coalesced out flush (64B segments) ----
        {
            int row = tid >> 4, hc = tid & 15;
            size_t oidx = ((size_t)(g * SPG + row) * TT + t) * HH + slot * HCB + hc;
            out[oidx] = hnew[row][hc];
            out[OSZ + oidx] = cnew[row][hc];
        }

        if (t + 1 < TT) {
            if (wv == 0) {
                // exchange: pack 4xbf16 per u64, one wave instruction (512B)
                int seq = lane >> 2, wd = lane & 3;
                unsigned long long pk =
                      (unsigned long long)bf16rne(hnew[seq][wd * 4 + 0])
                    | ((unsigned long long)bf16rne(hnew[seq][wd * 4 + 1]) << 16)
                    | ((unsigned long long)bf16rne(hnew[seq][wd * 4 + 2]) << 32)
                    | ((unsigned long long)bf16rne(hnew[seq][wd * 4 + 3]) << 48);
                size_t hidx = ((size_t)((t + 1) & 1) * 128 + g * SPG + seq) * 512
                            + slot * HCB + wd * 4;
                __hip_atomic_store((unsigned long long*)(hbuf + hidx), pk,
                                   __ATOMIC_RELAXED, __HIP_MEMORY_SCOPE_AGENT);
                asm volatile("s_waitcnt vmcnt(0)" ::: "memory");
                if (lane == 0)
                    __hip_atomic_store(&flags[(g * SLOTS + slot) * 16], (unsigned)(t + 1),
                                       __ATOMIC_RELAXED, __HIP_MEMORY_SCOPE_AGENT);
                // poll: 32 distinct flag lines, ballot across the wave
                const unsigned tgt = (unsigned)(t + 1);
                long gd = 0;
                for (;;) {
                    unsigned fl = (lane < SLOTS)
                        ? __hip_atomic_load(&flags[(g * SLOTS + lane) * 16],
                                            __ATOMIC_RELAXED, __HIP_MEMORY_SCOPE_AGENT)
                        : tgt;
                    if (__all(fl >= tgt)) break;
                    __builtin_amdgcn_s_sleep(1);
                    if (++gd > 50000000L) break;   // anti-hang escape
                }
                asm volatile("" ::: "memory");
            }
            __syncthreads();

            // ---- refill hsh with the group's h(t+1): 16 rows x 128 u64 ----
            const unsigned long long* src = (const unsigned long long*)
                (hbuf + ((size_t)((t + 1) & 1) * 128 + g * SPG) * 512);
            #pragma unroll
            for (int i = 0; i < 8; ++i) {
                int idx = i * 256 + tid;            // u64 index 0..2047
                unsigned long long d = __hip_atomic_load(src + idx,
                        __ATOMIC_RELAXED, __HIP_MEMORY_SCOPE_AGENT);
                int seq = idx >> 7;                 // 128 u64 per 512-bf16 row
                int k0  = (idx & 127) << 2;
                *(unsigned long long*)(hsh + seq * 512 + (k0 ^ ((seq & 7) << 3))) = d;
            }
            __syncthreads();
        }
    }
}

extern "C" void kernel_launch(void* const* d_in, const int* in_sizes, int n_in,
                              void* d_out, int out_size, void* d_ws, size_t ws_size,
                              hipStream_t stream) {
    const float* x    = (const float*)d_in[0];
    const float* wih  = (const float*)d_in[1];
    const float* whh  = (const float*)d_in[2];
    const float* bias = (const float*)d_in[3];
    float* out = (float*)d_out;
    float* ws  = (float*)d_ws;

    // zero the flag lines every launch (graph replay safe)
    hipMemsetAsync((char*)d_ws + 256 * 1024, 0, NGRP * SLOTS * 16 * sizeof(unsigned), stream);

    dim3 grid(NGRP * SLOTS), block(256);
    hipLaunchKernelGGL(lstm_mfma4, grid, block, 0, stream, x, wih, whh, bias, out, ws);
}